// Round 1
// 523.103 us; speedup vs baseline: 1.2685x; 1.2685x over previous
//
#include <hip/hip_runtime.h>
#include <hip/hip_bf16.h>
#include <cstdint>

#define N_NODES 100000
#define N_EDGES 1600000
#define F_IN    512
#define F_HID   128
#define F_OUT   40
#define F_OUT_PAD 48

// bucketed CSR build params
#define BSH    8                       // 256 nodes per bucket
#define NB     391                     // ceil(100000/256)
#define BEPT   8                       // edges per thread (bucket kernels)
#define BCHUNK 4096                    // 512 thr * 8 edges per block
#define GB     391                     // ceil(E / BCHUNK)
#define FCAP   6144                    // k_fine LDS record capacity (avg 4092, std 64)

typedef short v8s __attribute__((ext_vector_type(8)));
typedef float v4f __attribute__((ext_vector_type(4)));

__device__ __forceinline__ short f2bf(float f) {
    unsigned u = __float_as_uint(f);
    u += 0x7fffu + ((u >> 16) & 1u);
    return (short)(u >> 16);
}

__device__ __forceinline__ v8s pack8(float4 a, float4 b) {
    v8s r;
    r[0] = f2bf(a.x); r[1] = f2bf(a.y); r[2] = f2bf(a.z); r[3] = f2bf(a.w);
    r[4] = f2bf(b.x); r[5] = f2bf(b.y); r[6] = f2bf(b.z); r[7] = f2bf(b.w);
    return r;
}

// async 16B global->LDS (direct-to-shared DMA; LDS dest = wave-uniform base + lane*16)
__device__ __forceinline__ void gload16(const void* g, void* l) {
    __builtin_amdgcn_global_load_lds(
        (const __attribute__((address_space(1))) void*)g,
        (__attribute__((address_space(3))) void*)l, 16, 0, 0);
}

// ---------------- bucketed CSR build ----------------
// Level 1: 391 buckets of 256 nodes. All per-edge atomics live in LDS;
// global atomics are one per (block,bucket). All big global writes coalesced.

// A: bucket histogram (LDS-aggregated)
__global__ __launch_bounds__(512) void k_bhist(const int* __restrict__ dst,
                                               int* __restrict__ bcnt) {
    __shared__ int lh[512];
    int tid = threadIdx.x;
    lh[tid] = 0;
    __syncthreads();
    long e0 = (long)blockIdx.x * BCHUNK;
#pragma unroll
    for (int i = 0; i < BEPT; i++) {
        long e = e0 + tid + i * 512;
        if (e < N_EDGES) atomicAdd(&lh[dst[e] >> BSH], 1);
    }
    __syncthreads();
    if (tid < NB && lh[tid]) atomicAdd(&bcnt[tid], lh[tid]);
}

// scan bucket counts -> bucket bases; seed bucket cursors
__global__ __launch_bounds__(512) void k_bscan(const int* __restrict__ bcnt,
                                               int* __restrict__ bbase,
                                               int* __restrict__ bcur) {
    __shared__ int sm[512];
    int tid = threadIdx.x;
    int v = (tid < NB) ? bcnt[tid] : 0;
    sm[tid] = v;
    __syncthreads();
    for (int off = 1; off < 512; off <<= 1) {
        int t = (tid >= off) ? sm[tid - off] : 0;
        __syncthreads();
        sm[tid] += t;
        __syncthreads();
    }
    if (tid < NB) {
        int ex = sm[tid] - v;
        bbase[tid] = ex;
        bcur[tid] = ex;
    }
    if (tid == 511) bbase[NB] = sm[511];
}

// B: reorder edges into bucket-major tmp. Per-block LDS bucketing, then
// bucket-contiguous run writes (coalesced-ish, ~10 records/run).
// tmp record: (src | dstLow<<17, w_bits)  [src<2^17, dstLow<2^8]
__global__ __launch_bounds__(512) void k_bscatter(const int* __restrict__ src,
                                                  const int* __restrict__ dst,
                                                  const float* __restrict__ w,
                                                  int* __restrict__ bcur,
                                                  int2* __restrict__ tmp) {
    __shared__ int cntA[512];
    __shared__ int ofsA[512];
    __shared__ int lcur[512];
    __shared__ int gb[512];
    __shared__ __align__(16) int2 recBuf[BCHUNK];
    __shared__ unsigned short bkt[BCHUNK];
    int tid = threadIdx.x;
    long e0 = (long)blockIdx.x * BCHUNK;
    cntA[tid] = 0;
    __syncthreads();

    int dloc[BEPT];
#pragma unroll
    for (int i = 0; i < BEPT; i++) {
        long e = e0 + tid + i * 512;
        int d = (e < N_EDGES) ? dst[e] : -1;
        dloc[i] = d;
        if (d >= 0) atomicAdd(&cntA[d >> BSH], 1);
    }
    __syncthreads();

    // exclusive scan of cntA into ofsA
    int v = cntA[tid];
    ofsA[tid] = v;
    __syncthreads();
    for (int off = 1; off < 512; off <<= 1) {
        int t = (tid >= off) ? ofsA[tid - off] : 0;
        __syncthreads();
        ofsA[tid] += t;
        __syncthreads();
    }
    int excl = ofsA[tid] - v;
    ofsA[tid] = excl;          // own-slot rewrite; no cross-read of inclusive after
    lcur[tid] = excl;
    if (tid < NB && v > 0) gb[tid] = atomicAdd(&bcur[tid], v);
    __syncthreads();

    // stage records bucket-ordered in LDS
#pragma unroll
    for (int i = 0; i < BEPT; i++) {
        int d = dloc[i];
        if (d >= 0) {
            long e = e0 + tid + i * 512;
            int j = d >> BSH;
            int slot = atomicAdd(&lcur[j], 1);
            recBuf[slot] = make_int2(src[e] | ((d & 255) << 17), __float_as_int(w[e]));
            bkt[slot] = (unsigned short)j;
        }
    }
    __syncthreads();

    long rem = N_EDGES - e0;
    int total = (rem < BCHUNK) ? (int)rem : BCHUNK;
    for (int s = tid; s < total; s += 512) {
        int j = bkt[s];
        tmp[gb[j] + (s - ofsA[j])] = recBuf[s];
    }
}

// C: per-bucket fine sort by node; emits rowptr/deg directly (replaces the
// global node scan + hist) and writes rec fully coalesced.
__global__ __launch_bounds__(256) void k_fine(const int2* __restrict__ tmp,
                                              const int* __restrict__ bbase,
                                              int2* __restrict__ rec,
                                              int* __restrict__ rowptr,
                                              int* __restrict__ deg) {
    __shared__ int hist[256];
    __shared__ int ofs[256];
    __shared__ int cur[256];
    __shared__ __align__(16) int2 recOut[FCAP];
    int tid = threadIdx.x, b = blockIdx.x;
    int base = bbase[b];
    int cnt = bbase[b + 1] - base;

    hist[tid] = 0;
    __syncthreads();
    for (int i = tid; i < cnt; i += 256) {
        unsigned u = (unsigned)tmp[base + i].x;
        atomicAdd(&hist[u >> 17], 1);
    }
    __syncthreads();

    int v = hist[tid];
    ofs[tid] = v;
    __syncthreads();
    for (int off = 1; off < 256; off <<= 1) {
        int t = (tid >= off) ? ofs[tid - off] : 0;
        __syncthreads();
        ofs[tid] += t;
        __syncthreads();
    }
    int excl = ofs[tid] - v;
    ofs[tid] = excl;
    cur[tid] = excl;
    int node = (b << BSH) + tid;
    if (node < N_NODES) {
        rowptr[node] = base + excl;
        deg[node] = v;
    }
    __syncthreads();

    if (cnt <= FCAP) {
        for (int i = tid; i < cnt; i += 256) {
            int2 r = tmp[base + i];
            unsigned u = (unsigned)r.x;
            int slot = atomicAdd(&cur[u >> 17], 1);
            recOut[slot] = make_int2((int)(u & 0x1FFFFu), r.y);
        }
        __syncthreads();
        for (int i = tid; i < cnt; i += 256) rec[base + i] = recOut[i];
    } else { // statistically unreachable overflow fallback (still correct)
        for (int i = tid; i < cnt; i += 256) {
            int2 r = tmp[base + i];
            unsigned u = (unsigned)r.x;
            int slot = atomicAdd(&cur[u >> 17], 1);
            rec[base + slot] = make_int2((int)(u & 0x1FFFFu), r.y);
        }
    }
}

// ---------------- weight transpose+convert ----------------

__global__ void k_convW(const float* __restrict__ W1, short* __restrict__ WT1,
                        const float* __restrict__ W2, short* __restrict__ WT2) {
    int i = blockIdx.x * blockDim.x + threadIdx.x;
    if (i < F_IN * F_HID) {            // i = n*512 + k
        int n = i >> 9, k = i & 511;
        WT1[i] = f2bf(W1[k * F_HID + n]);
    } else {
        int j = i - F_IN * F_HID;      // j = n*128 + k
        if (j < F_OUT_PAD * F_HID) {
            int n = j >> 7, k = j & 127;
            WT2[j] = (n < F_OUT) ? f2bf(W2[k * F_OUT + n]) : (short)0;
        }
    }
}

// ---------------- GEMM1 (LDS-staged, m97-style): m1b = x @ W1 ----------------
// Block: 256 thr (4 waves), tile M=64 x N=128, BK=32, double-buffered
// global_load_lds staging. XOR swizzle keeps DMA contiguous and LDS reads
// <=2-way (free). A staged fp32 (converted post-LDS-read), B staged bf16.

__global__ __launch_bounds__(256) void k_gemm1(const float* __restrict__ x,
                                               const short* __restrict__ WT1,
                                               unsigned short* __restrict__ m1b) {
    __shared__ __align__(16) float aBuf[2][64 * 32];  // 2 x 8 KB
    __shared__ __align__(16) short bBuf[2][128 * 32]; // 2 x 8 KB
    int tid = threadIdx.x, w = tid >> 6, lane = tid & 63;
    int quad = lane >> 4, l16 = lane & 15;
    long rowBase = (long)blockIdx.x * 64;

    // staging lane decomposition
    int ar = lane >> 3, ac = lane & 7; // A: 8 rows x 8 kblocks(16B=4 floats)
    int br = lane >> 2, bc = lane & 3; // B: 16 rows x 4 kblocks(16B=8 bf16)

    v4f acc[8];
#pragma unroll
    for (int t = 0; t < 8; t++) acc[t] = (v4f){0.f, 0.f, 0.f, 0.f};

    // --- stage chunk kc into buffer buf ---
    auto stage = [&](int kc, int buf) {
#pragma unroll
        for (int i = 0; i < 2; i++) { // A: wave w stages rows w*16 .. +15
            int rl = w * 16 + i * 8 + ar;
            long rg = rowBase + rl;
            if (rg > N_NODES - 1) rg = N_NODES - 1; // tail clamp (dup, harmless)
            const float* gp = x + rg * F_IN + kc * 32 + ((ac ^ (rl & 7)) << 2);
            gload16(gp, &aBuf[buf][(w * 16 + i * 8) * 32]);
        }
#pragma unroll
        for (int i = 0; i < 2; i++) { // B: wave w stages n-rows w*32 .. +31
            int n = w * 32 + i * 16 + br;
            const short* gp = WT1 + n * F_IN + kc * 32 + ((bc ^ ((n >> 1) & 3)) << 3);
            gload16(gp, &bBuf[buf][(w * 32 + i * 16) * 32]);
        }
    };

    stage(0, 0);
#pragma unroll
    for (int kc = 0; kc < 16; kc++) {
        __syncthreads(); // drains global_load_lds (vmcnt) + all-wave arrival
        int buf = kc & 1;
        if (kc < 15) stage(kc + 1, buf ^ 1);
        // A-frag: rows w*16+l16, k = quad*8+j ; swizzled kblock p = (2q)^(r&7)
        int arow = w * 16 + l16;
        int p0 = (2 * quad) ^ (l16 & 7);
        float4 av0 = *(const float4*)&aBuf[buf][arow * 32 + p0 * 4];
        float4 av1 = *(const float4*)&aBuf[buf][arow * 32 + (p0 ^ 1) * 4];
        v8s af = pack8(av0, av1);
#pragma unroll
        for (int t = 0; t < 8; t++) {
            int n = t * 16 + l16;
            int p = quad ^ ((n >> 1) & 3);
            v8s bf = *(const v8s*)&bBuf[buf][n * 32 + p * 8];
            acc[t] = __builtin_amdgcn_mfma_f32_16x16x32_bf16(af, bf, acc[t], 0, 0, 0);
        }
    }

#pragma unroll
    for (int t = 0; t < 8; t++)
#pragma unroll
        for (int r = 0; r < 4; r++) {
            long row = rowBase + w * 16 + quad * 4 + r;
            if (row < N_NODES)
                m1b[row * F_HID + t * 16 + l16] = (unsigned short)f2bf(acc[t][r]);
        }
}

// ---------------- layer-1 aggregation: wave/node, bf16x2 per lane, 4-edge unroll ----

__global__ void k_agg1(const int2* __restrict__ rec, const int* __restrict__ rowptr,
                       const int* __restrict__ deg, const unsigned* __restrict__ m1u,
                       const float* __restrict__ b1, unsigned* __restrict__ h) {
    int node = blockIdx.x * 4 + (threadIdx.x >> 6);
    int lane = threadIdx.x & 63;
    if (node >= N_NODES) return;
    int start = rowptr[node], cnt = deg[node];

    float ax0 = 0.f, ay0 = 0.f, ax1 = 0.f, ay1 = 0.f;
    float ax2 = 0.f, ay2 = 0.f, ax3 = 0.f, ay3 = 0.f;
    int i = 0;
    for (; i + 4 <= cnt; i += 4) {
        int2 r0 = rec[start + i + 0];
        int2 r1 = rec[start + i + 1];
        int2 r2 = rec[start + i + 2];
        int2 r3 = rec[start + i + 3];
        unsigned u0 = m1u[(long)r0.x * 64 + lane];
        unsigned u1 = m1u[(long)r1.x * 64 + lane];
        unsigned u2 = m1u[(long)r2.x * 64 + lane];
        unsigned u3 = m1u[(long)r3.x * 64 + lane];
        float w0 = __int_as_float(r0.y), w1 = __int_as_float(r1.y);
        float w2 = __int_as_float(r2.y), w3 = __int_as_float(r3.y);
        ax0 = fmaf(w0, __uint_as_float(u0 << 16), ax0);
        ay0 = fmaf(w0, __uint_as_float(u0 & 0xffff0000u), ay0);
        ax1 = fmaf(w1, __uint_as_float(u1 << 16), ax1);
        ay1 = fmaf(w1, __uint_as_float(u1 & 0xffff0000u), ay1);
        ax2 = fmaf(w2, __uint_as_float(u2 << 16), ax2);
        ay2 = fmaf(w2, __uint_as_float(u2 & 0xffff0000u), ay2);
        ax3 = fmaf(w3, __uint_as_float(u3 << 16), ax3);
        ay3 = fmaf(w3, __uint_as_float(u3 & 0xffff0000u), ay3);
    }
    for (; i < cnt; i++) {
        int2 r = rec[start + i];
        unsigned u = m1u[(long)r.x * 64 + lane];
        float w = __int_as_float(r.y);
        ax0 = fmaf(w, __uint_as_float(u << 16), ax0);
        ay0 = fmaf(w, __uint_as_float(u & 0xffff0000u), ay0);
    }
    float accx = (ax0 + ax1) + (ax2 + ax3) + b1[2 * lane];
    float accy = (ay0 + ay1) + (ay2 + ay3) + b1[2 * lane + 1];
    accx = fmaxf(accx, 0.f);
    accy = fmaxf(accy, 0.f);
    unsigned packed = (unsigned)(unsigned short)f2bf(accx) |
                      ((unsigned)(unsigned short)f2bf(accy) << 16);
    h[(long)node * 64 + lane] = packed; // h is bf16[100000][128]
}

// ---------------- GEMM2: m2b[100000,64] (bf16) = h @ W2; cols 40..63 zero ----------

__global__ __launch_bounds__(256) void k_gemm2(const unsigned short* __restrict__ h,
                                               const short* __restrict__ WT2,
                                               unsigned short* __restrict__ m2b) {
    int wave = threadIdx.x >> 6, lane = threadIdx.x & 63;
    int quad = lane >> 4, l16 = lane & 15;
    long rowBase = ((long)blockIdx.x * 4 + wave) * 16;
    if (rowBase >= N_NODES) return;

    v4f acc[3];
#pragma unroll
    for (int t = 0; t < 3; t++) acc[t] = (v4f){0.f, 0.f, 0.f, 0.f};

    const short* arow = (const short*)h + (rowBase + l16) * (long)F_HID + quad * 8;
    const short* brow = WT2 + l16 * F_HID + quad * 8;
#pragma unroll
    for (int k0 = 0; k0 < F_HID; k0 += 32) {
        v8s af = *reinterpret_cast<const v8s*>(arow + k0);
#pragma unroll
        for (int t = 0; t < 3; t++) {
            v8s bf = *reinterpret_cast<const v8s*>(brow + t * 16 * F_HID + k0);
            acc[t] = __builtin_amdgcn_mfma_f32_16x16x32_bf16(af, bf, acc[t], 0, 0, 0);
        }
    }
#pragma unroll
    for (int r = 0; r < 4; r++) {
        long row = rowBase + quad * 4 + r;
#pragma unroll
        for (int t = 0; t < 3; t++)
            m2b[row * 64 + t * 16 + l16] = (unsigned short)f2bf(acc[t][r]);
        m2b[row * 64 + 48 + l16] = 0;
    }
}

// ---------------- layer-2 aggregation + bias + log_softmax (bf16 gather) ----------

__global__ void k_agg2(const int2* __restrict__ rec, const int* __restrict__ rowptr,
                       const int* __restrict__ deg, const unsigned short* __restrict__ m2b,
                       const float* __restrict__ b2, float* __restrict__ out) {
    int node = blockIdx.x * 4 + (threadIdx.x >> 6);
    int lane = threadIdx.x & 63;
    if (node >= N_NODES) return;
    int start = rowptr[node], cnt = deg[node];

    float a0 = 0.f, a1 = 0.f, a2 = 0.f, a3 = 0.f;
    int i = 0;
    for (; i + 4 <= cnt; i += 4) {
        int2 r0 = rec[start + i + 0];
        int2 r1 = rec[start + i + 1];
        int2 r2 = rec[start + i + 2];
        int2 r3 = rec[start + i + 3];
        unsigned short u0 = m2b[(long)r0.x * 64 + lane];
        unsigned short u1 = m2b[(long)r1.x * 64 + lane];
        unsigned short u2 = m2b[(long)r2.x * 64 + lane];
        unsigned short u3 = m2b[(long)r3.x * 64 + lane];
        a0 = fmaf(__int_as_float(r0.y), __uint_as_float((unsigned)u0 << 16), a0);
        a1 = fmaf(__int_as_float(r1.y), __uint_as_float((unsigned)u1 << 16), a1);
        a2 = fmaf(__int_as_float(r2.y), __uint_as_float((unsigned)u2 << 16), a2);
        a3 = fmaf(__int_as_float(r3.y), __uint_as_float((unsigned)u3 << 16), a3);
    }
    for (; i < cnt; i++) {
        int2 r = rec[start + i];
        unsigned short u = m2b[(long)r.x * 64 + lane];
        a0 = fmaf(__int_as_float(r.y), __uint_as_float((unsigned)u << 16), a0);
    }
    float acc = (a0 + a1) + (a2 + a3);
    if (lane < F_OUT) acc += b2[lane];
    float p = (lane < F_OUT) ? acc : -3.4e38f;
#pragma unroll
    for (int off = 32; off; off >>= 1) p = fmaxf(p, __shfl_xor(p, off));
    float ex = (lane < F_OUT) ? __expf(acc - p) : 0.f;
    float s = ex;
#pragma unroll
    for (int off = 32; off; off >>= 1) s += __shfl_xor(s, off);
    if (lane < F_OUT) out[(long)node * F_OUT + lane] = acc - p - __logf(s);
}

// ---------------- launch ----------------

extern "C" void kernel_launch(void* const* d_in, const int* in_sizes, int n_in,
                              void* d_out, int out_size, void* d_ws, size_t ws_size,
                              hipStream_t stream) {
    const float* x  = (const float*)d_in[0];
    const int* ei   = (const int*)d_in[1]; // [2, E]: src then dst (int32)
    const int* src  = ei;
    const int* dst  = ei + N_EDGES;
    const float* ew = (const float*)d_in[2];
    const float* W1 = (const float*)d_in[3];
    const float* b1 = (const float*)d_in[4];
    const float* W2 = (const float*)d_in[5];
    const float* b2 = (const float*)d_in[6];
    float* out = (float*)d_out;

    char* ws = (char*)d_ws;
    size_t off = 0;
    auto alloc = [&](size_t bytes) {
        void* p = ws + off;
        off += (bytes + 255) & ~(size_t)255;
        return p;
    };
    unsigned short* m1b  = (unsigned short*)alloc((size_t)N_NODES * F_HID * 2); // 25.6 MB
    unsigned int*   h    = (unsigned int*)alloc((size_t)N_NODES * F_HID * 2);   // 25.6 MB
    unsigned short* m2b  = (unsigned short*)alloc((size_t)N_NODES * 64 * 2);    // 12.8 MB
    int2*           rec  = (int2*)alloc((size_t)N_EDGES * 8);                   // 12.8 MB
    int*          rowptr = (int*)alloc((size_t)N_NODES * 4);
    int*          deg    = (int*)alloc((size_t)N_NODES * 4);
    int*          bCnt   = (int*)alloc(512 * 4);
    int*          bBase  = (int*)alloc(512 * 4);
    int*          bCur   = (int*)alloc(512 * 4);
    short*        WT1    = (short*)alloc((size_t)F_HID * F_IN * 2);
    short*        WT2    = (short*)alloc((size_t)F_OUT_PAD * F_HID * 2);

    // tmp (bucket-major edge records) aliases m2b: both 12.8 MB; tmp is dead
    // before k_gemm2 writes m2b.
    int2* tmp = (int2*)m2b;

    hipMemsetAsync(bCnt, 0, 512 * 4, stream);

    int convTot = F_IN * F_HID + F_OUT_PAD * F_HID;
    k_convW<<<(convTot + 255) / 256, 256, 0, stream>>>(W1, WT1, W2, WT2);

    k_bhist<<<GB, 512, 0, stream>>>(dst, bCnt);
    k_bscan<<<1, 512, 0, stream>>>(bCnt, bBase, bCur);
    k_bscatter<<<GB, 512, 0, stream>>>(src, dst, ew, bCur, tmp);
    k_fine<<<NB, 256, 0, stream>>>(tmp, bBase, rec, rowptr, deg);

    k_gemm1<<<(N_NODES + 63) / 64, 256, 0, stream>>>(x, WT1, m1b);
    k_agg1<<<(N_NODES + 3) / 4, 256, 0, stream>>>(rec, rowptr, deg, (const unsigned*)m1b, b1, h);
    k_gemm2<<<(N_NODES + 63) / 64, 256, 0, stream>>>((const unsigned short*)h, WT2, m2b);
    k_agg2<<<(N_NODES + 3) / 4, 256, 0, stream>>>(rec, rowptr, deg, m2b, b2, out);
}

// Round 2
// 497.602 us; speedup vs baseline: 1.3335x; 1.0512x over previous
//
#include <hip/hip_runtime.h>
#include <hip/hip_bf16.h>
#include <cstdint>

#define N_NODES 100000
#define N_EDGES 1600000
#define F_IN    512
#define F_HID   128
#define F_OUT   40
#define F_OUT_PAD 48

// bucketed CSR build params
#define BSH    8                       // 256 nodes per bucket
#define NB     391                     // ceil(100000/256)
#define BEPT   8                       // edges per thread (bucket kernels)
#define BCHUNK 4096                    // 512 thr * 8 edges per block
#define GB     391                     // ceil(E / BCHUNK)
#define CONVB  140                     // conv blocks appended to bhist grid
#define FCAP   6144                    // k_fine LDS record capacity (avg 4092, std 64)

typedef short v8s __attribute__((ext_vector_type(8)));
typedef float v4f __attribute__((ext_vector_type(4)));

__device__ __forceinline__ short f2bf(float f) {
    unsigned u = __float_as_uint(f);
    u += 0x7fffu + ((u >> 16) & 1u);
    return (short)(u >> 16);
}

__device__ __forceinline__ float bflo(unsigned u) { return __uint_as_float(u << 16); }
__device__ __forceinline__ float bfhi(unsigned u) { return __uint_as_float(u & 0xffff0000u); }

__device__ __forceinline__ v8s pack8(float4 a, float4 b) {
    v8s r;
    r[0] = f2bf(a.x); r[1] = f2bf(a.y); r[2] = f2bf(a.z); r[3] = f2bf(a.w);
    r[4] = f2bf(b.x); r[5] = f2bf(b.y); r[6] = f2bf(b.z); r[7] = f2bf(b.w);
    return r;
}

// async 16B global->LDS (direct-to-shared DMA; LDS dest = wave-uniform base + lane*16)
__device__ __forceinline__ void gload16(const void* g, void* l) {
    __builtin_amdgcn_global_load_lds(
        (const __attribute__((address_space(1))) void*)g,
        (__attribute__((address_space(3))) void*)l, 16, 0, 0);
}

// ---------------- bucketed CSR build ----------------
// Level 1: 391 buckets of 256 nodes. All per-edge atomics live in LDS;
// global atomics are one per (block,bucket). All big global writes coalesced.

// A: bucket histogram (LDS-aggregated) + weight convert (independent blocks)
__global__ __launch_bounds__(512) void k_bhist(const int* __restrict__ dst,
                                               int* __restrict__ bcnt,
                                               const float* __restrict__ W1,
                                               short* __restrict__ WT1,
                                               const float* __restrict__ W2,
                                               short* __restrict__ WT2) {
    if (blockIdx.x >= GB) { // weight transpose+convert tail blocks
        int i = (blockIdx.x - GB) * 512 + threadIdx.x;
        if (i < F_IN * F_HID) {            // i = n*512 + k
            int n = i >> 9, k = i & 511;
            WT1[i] = f2bf(W1[k * F_HID + n]);
        } else {
            int j = i - F_IN * F_HID;      // j = n*128 + k
            if (j < F_OUT_PAD * F_HID) {
                int n = j >> 7, k = j & 127;
                WT2[j] = (n < F_OUT) ? f2bf(W2[k * F_OUT + n]) : (short)0;
            }
        }
        return;
    }
    __shared__ int lh[512];
    int tid = threadIdx.x;
    lh[tid] = 0;
    __syncthreads();
    long e0 = (long)blockIdx.x * BCHUNK;
#pragma unroll
    for (int i = 0; i < BEPT; i++) {
        long e = e0 + tid + i * 512;
        if (e < N_EDGES) atomicAdd(&lh[dst[e] >> BSH], 1);
    }
    __syncthreads();
    if (tid < NB && lh[tid]) atomicAdd(&bcnt[tid], lh[tid]);
}

// scan bucket counts -> bucket bases; seed bucket cursors
__global__ __launch_bounds__(512) void k_bscan(const int* __restrict__ bcnt,
                                               int* __restrict__ bbase,
                                               int* __restrict__ bcur) {
    __shared__ int sm[512];
    int tid = threadIdx.x;
    int v = (tid < NB) ? bcnt[tid] : 0;
    sm[tid] = v;
    __syncthreads();
    for (int off = 1; off < 512; off <<= 1) {
        int t = (tid >= off) ? sm[tid - off] : 0;
        __syncthreads();
        sm[tid] += t;
        __syncthreads();
    }
    if (tid < NB) {
        int ex = sm[tid] - v;
        bbase[tid] = ex;
        bcur[tid] = ex;
    }
    if (tid == 511) bbase[NB] = sm[511];
}

// B: reorder edges into bucket-major tmp. Per-block LDS bucketing, then
// bucket-contiguous run writes (coalesced-ish, ~10 records/run).
// tmp record: (src | dstLow<<17, w_bits)  [src<2^17, dstLow<2^8]
__global__ __launch_bounds__(512) void k_bscatter(const int* __restrict__ src,
                                                  const int* __restrict__ dst,
                                                  const float* __restrict__ w,
                                                  int* __restrict__ bcur,
                                                  int2* __restrict__ tmp) {
    __shared__ int cntA[512];
    __shared__ int ofsA[512];
    __shared__ int lcur[512];
    __shared__ int gb[512];
    __shared__ __align__(16) int2 recBuf[BCHUNK];
    __shared__ unsigned short bkt[BCHUNK];
    int tid = threadIdx.x;
    long e0 = (long)blockIdx.x * BCHUNK;
    cntA[tid] = 0;
    __syncthreads();

    int dloc[BEPT];
#pragma unroll
    for (int i = 0; i < BEPT; i++) {
        long e = e0 + tid + i * 512;
        int d = (e < N_EDGES) ? dst[e] : -1;
        dloc[i] = d;
        if (d >= 0) atomicAdd(&cntA[d >> BSH], 1);
    }
    __syncthreads();

    // exclusive scan of cntA into ofsA
    int v = cntA[tid];
    ofsA[tid] = v;
    __syncthreads();
    for (int off = 1; off < 512; off <<= 1) {
        int t = (tid >= off) ? ofsA[tid - off] : 0;
        __syncthreads();
        ofsA[tid] += t;
        __syncthreads();
    }
    int excl = ofsA[tid] - v;
    ofsA[tid] = excl;          // own-slot rewrite; no cross-read of inclusive after
    lcur[tid] = excl;
    if (tid < NB && v > 0) gb[tid] = atomicAdd(&bcur[tid], v);
    __syncthreads();

    // stage records bucket-ordered in LDS
#pragma unroll
    for (int i = 0; i < BEPT; i++) {
        int d = dloc[i];
        if (d >= 0) {
            long e = e0 + tid + i * 512;
            int j = d >> BSH;
            int slot = atomicAdd(&lcur[j], 1);
            recBuf[slot] = make_int2(src[e] | ((d & 255) << 17), __float_as_int(w[e]));
            bkt[slot] = (unsigned short)j;
        }
    }
    __syncthreads();

    long rem = N_EDGES - e0;
    int total = (rem < BCHUNK) ? (int)rem : BCHUNK;
    for (int s = tid; s < total; s += 512) {
        int j = bkt[s];
        tmp[gb[j] + (s - ofsA[j])] = recBuf[s];
    }
}

// C: per-bucket fine sort by node; emits rowptr/deg directly and writes rec
// fully coalesced.
__global__ __launch_bounds__(256) void k_fine(const int2* __restrict__ tmp,
                                              const int* __restrict__ bbase,
                                              int2* __restrict__ rec,
                                              int* __restrict__ rowptr,
                                              int* __restrict__ deg) {
    __shared__ int hist[256];
    __shared__ int ofs[256];
    __shared__ int cur[256];
    __shared__ __align__(16) int2 recOut[FCAP];
    int tid = threadIdx.x, b = blockIdx.x;
    int base = bbase[b];
    int cnt = bbase[b + 1] - base;

    hist[tid] = 0;
    __syncthreads();
    for (int i = tid; i < cnt; i += 256) {
        unsigned u = (unsigned)tmp[base + i].x;
        atomicAdd(&hist[u >> 17], 1);
    }
    __syncthreads();

    int v = hist[tid];
    ofs[tid] = v;
    __syncthreads();
    for (int off = 1; off < 256; off <<= 1) {
        int t = (tid >= off) ? ofs[tid - off] : 0;
        __syncthreads();
        ofs[tid] += t;
        __syncthreads();
    }
    int excl = ofs[tid] - v;
    ofs[tid] = excl;
    cur[tid] = excl;
    int node = (b << BSH) + tid;
    if (node < N_NODES) {
        rowptr[node] = base + excl;
        deg[node] = v;
    }
    __syncthreads();

    if (cnt <= FCAP) {
        for (int i = tid; i < cnt; i += 256) {
            int2 r = tmp[base + i];
            unsigned u = (unsigned)r.x;
            int slot = atomicAdd(&cur[u >> 17], 1);
            recOut[slot] = make_int2((int)(u & 0x1FFFFu), r.y);
        }
        __syncthreads();
        for (int i = tid; i < cnt; i += 256) rec[base + i] = recOut[i];
    } else { // statistically unreachable overflow fallback (still correct)
        for (int i = tid; i < cnt; i += 256) {
            int2 r = tmp[base + i];
            unsigned u = (unsigned)r.x;
            int slot = atomicAdd(&cur[u >> 17], 1);
            rec[base + slot] = make_int2((int)(u & 0x1FFFFu), r.y);
        }
    }
}

// ---------------- GEMM1 (LDS-staged, m97-style): m1b = x @ W1 ----------------
// Block: 256 thr (4 waves), tile M=64 x N=128, BK=32, double-buffered
// global_load_lds staging. XOR swizzle keeps DMA contiguous and LDS reads
// <=2-way (free). A staged fp32 (converted post-LDS-read), B staged bf16.

__global__ __launch_bounds__(256) void k_gemm1(const float* __restrict__ x,
                                               const short* __restrict__ WT1,
                                               unsigned short* __restrict__ m1b) {
    __shared__ __align__(16) float aBuf[2][64 * 32];  // 2 x 8 KB
    __shared__ __align__(16) short bBuf[2][128 * 32]; // 2 x 8 KB
    int tid = threadIdx.x, w = tid >> 6, lane = tid & 63;
    int quad = lane >> 4, l16 = lane & 15;
    long rowBase = (long)blockIdx.x * 64;

    // staging lane decomposition
    int ar = lane >> 3, ac = lane & 7; // A: 8 rows x 8 kblocks(16B=4 floats)
    int br = lane >> 2, bc = lane & 3; // B: 16 rows x 4 kblocks(16B=8 bf16)

    v4f acc[8];
#pragma unroll
    for (int t = 0; t < 8; t++) acc[t] = (v4f){0.f, 0.f, 0.f, 0.f};

    // --- stage chunk kc into buffer buf ---
    auto stage = [&](int kc, int buf) {
#pragma unroll
        for (int i = 0; i < 2; i++) { // A: wave w stages rows w*16 .. +15
            int rl = w * 16 + i * 8 + ar;
            long rg = rowBase + rl;
            if (rg > N_NODES - 1) rg = N_NODES - 1; // tail clamp (dup, harmless)
            const float* gp = x + rg * F_IN + kc * 32 + ((ac ^ (rl & 7)) << 2);
            gload16(gp, &aBuf[buf][(w * 16 + i * 8) * 32]);
        }
#pragma unroll
        for (int i = 0; i < 2; i++) { // B: wave w stages n-rows w*32 .. +31
            int n = w * 32 + i * 16 + br;
            const short* gp = WT1 + n * F_IN + kc * 32 + ((bc ^ ((n >> 1) & 3)) << 3);
            gload16(gp, &bBuf[buf][(w * 32 + i * 16) * 32]);
        }
    };

    stage(0, 0);
#pragma unroll
    for (int kc = 0; kc < 16; kc++) {
        __syncthreads(); // drains global_load_lds (vmcnt) + all-wave arrival
        int buf = kc & 1;
        if (kc < 15) stage(kc + 1, buf ^ 1);
        // A-frag: rows w*16+l16, k = quad*8+j ; swizzled kblock p = (2q)^(r&7)
        int arow = w * 16 + l16;
        int p0 = (2 * quad) ^ (l16 & 7);
        float4 av0 = *(const float4*)&aBuf[buf][arow * 32 + p0 * 4];
        float4 av1 = *(const float4*)&aBuf[buf][arow * 32 + (p0 ^ 1) * 4];
        v8s af = pack8(av0, av1);
#pragma unroll
        for (int t = 0; t < 8; t++) {
            int n = t * 16 + l16;
            int p = quad ^ ((n >> 1) & 3);
            v8s bf = *(const v8s*)&bBuf[buf][n * 32 + p * 8];
            acc[t] = __builtin_amdgcn_mfma_f32_16x16x32_bf16(af, bf, acc[t], 0, 0, 0);
        }
    }

#pragma unroll
    for (int t = 0; t < 8; t++)
#pragma unroll
        for (int r = 0; r < 4; r++) {
            long row = rowBase + w * 16 + quad * 4 + r;
            if (row < N_NODES)
                m1b[row * F_HID + t * 16 + l16] = (unsigned short)f2bf(acc[t][r]);
        }
}

// ---------------- layer-1 aggregation: wave/node, HALF-WAVE per edge --------
// Each lane covers 8 B (uint2 = 4 bf16 features) of the 256 B row; lanes
// 0-31 process even edges, 32-63 odd edges. One dwordx2 gather covers 2
// edges -> 2x fewer memory instructions than the 4 B/lane version.

__global__ void k_agg1(const int2* __restrict__ rec, const int* __restrict__ rowptr,
                       const int* __restrict__ deg, const uint2* __restrict__ m1v,
                       const float* __restrict__ b1, uint2* __restrict__ h2) {
    int node = blockIdx.x * 4 + (threadIdx.x >> 6);
    int lane = threadIdx.x & 63;
    if (node >= N_NODES) return;
    int half = lane >> 5, l32 = lane & 31;
    int start = rowptr[node], cnt = deg[node];

    float a0 = 0.f, a1 = 0.f, a2 = 0.f, a3 = 0.f;
    float c0 = 0.f, c1 = 0.f, c2 = 0.f, c3 = 0.f;

    int nmain = cnt >> 3; // 8 edges per iter (4 per half)
    int ebase = start + half;
    for (int k = 0; k < nmain; k++) {
        int e = ebase + (k << 3);
        int2 r0 = rec[e];
        int2 r1 = rec[e + 2];
        int2 r2 = rec[e + 4];
        int2 r3 = rec[e + 6];
        uint2 g0 = m1v[(long)r0.x * 32 + l32];
        uint2 g1 = m1v[(long)r1.x * 32 + l32];
        uint2 g2 = m1v[(long)r2.x * 32 + l32];
        uint2 g3 = m1v[(long)r3.x * 32 + l32];
        float w0 = __int_as_float(r0.y), w1 = __int_as_float(r1.y);
        float w2 = __int_as_float(r2.y), w3 = __int_as_float(r3.y);
        a0 = fmaf(w0, bflo(g0.x), a0); a1 = fmaf(w0, bfhi(g0.x), a1);
        a2 = fmaf(w0, bflo(g0.y), a2); a3 = fmaf(w0, bfhi(g0.y), a3);
        c0 = fmaf(w1, bflo(g1.x), c0); c1 = fmaf(w1, bfhi(g1.x), c1);
        c2 = fmaf(w1, bflo(g1.y), c2); c3 = fmaf(w1, bfhi(g1.y), c3);
        a0 = fmaf(w2, bflo(g2.x), a0); a1 = fmaf(w2, bfhi(g2.x), a1);
        a2 = fmaf(w2, bflo(g2.y), a2); a3 = fmaf(w2, bfhi(g2.y), a3);
        c0 = fmaf(w3, bflo(g3.x), c0); c1 = fmaf(w3, bfhi(g3.x), c1);
        c2 = fmaf(w3, bflo(g3.y), c2); c3 = fmaf(w3, bfhi(g3.y), c3);
    }
    for (int e = start + (nmain << 3) + half; e < start + cnt; e += 2) {
        int2 r = rec[e];
        uint2 g = m1v[(long)r.x * 32 + l32];
        float w = __int_as_float(r.y);
        a0 = fmaf(w, bflo(g.x), a0); a1 = fmaf(w, bfhi(g.x), a1);
        a2 = fmaf(w, bflo(g.y), a2); a3 = fmaf(w, bfhi(g.y), a3);
    }
    a0 += c0; a1 += c1; a2 += c2; a3 += c3;
    a0 += __shfl_xor(a0, 32);
    a1 += __shfl_xor(a1, 32);
    a2 += __shfl_xor(a2, 32);
    a3 += __shfl_xor(a3, 32);
    if (half == 0) {
        float4 bv = ((const float4*)b1)[l32];
        a0 = fmaxf(a0 + bv.x, 0.f);
        a1 = fmaxf(a1 + bv.y, 0.f);
        a2 = fmaxf(a2 + bv.z, 0.f);
        a3 = fmaxf(a3 + bv.w, 0.f);
        unsigned lo = (unsigned)(unsigned short)f2bf(a0) |
                      ((unsigned)(unsigned short)f2bf(a1) << 16);
        unsigned hi = (unsigned)(unsigned short)f2bf(a2) |
                      ((unsigned)(unsigned short)f2bf(a3) << 16);
        h2[(long)node * 32 + l32] = make_uint2(lo, hi);
    }
}

// ---------------- GEMM2: m2b[100000,64] (bf16) = h @ W2; cols 40..63 zero ----------

__global__ __launch_bounds__(256) void k_gemm2(const unsigned short* __restrict__ h,
                                               const short* __restrict__ WT2,
                                               unsigned short* __restrict__ m2b) {
    int wave = threadIdx.x >> 6, lane = threadIdx.x & 63;
    int quad = lane >> 4, l16 = lane & 15;
    long rowBase = ((long)blockIdx.x * 4 + wave) * 16;
    if (rowBase >= N_NODES) return;

    v4f acc[3];
#pragma unroll
    for (int t = 0; t < 3; t++) acc[t] = (v4f){0.f, 0.f, 0.f, 0.f};

    const short* arow = (const short*)h + (rowBase + l16) * (long)F_HID + quad * 8;
    const short* brow = WT2 + l16 * F_HID + quad * 8;
#pragma unroll
    for (int k0 = 0; k0 < F_HID; k0 += 32) {
        v8s af = *reinterpret_cast<const v8s*>(arow + k0);
#pragma unroll
        for (int t = 0; t < 3; t++) {
            v8s bf = *reinterpret_cast<const v8s*>(brow + t * 16 * F_HID + k0);
            acc[t] = __builtin_amdgcn_mfma_f32_16x16x32_bf16(af, bf, acc[t], 0, 0, 0);
        }
    }
#pragma unroll
    for (int r = 0; r < 4; r++) {
        long row = rowBase + quad * 4 + r;
#pragma unroll
        for (int t = 0; t < 3; t++)
            m2b[row * 64 + t * 16 + l16] = (unsigned short)f2bf(acc[t][r]);
        m2b[row * 64 + 48 + l16] = 0;
    }
}

// ---------------- layer-2 aggregation + bias + log_softmax ------------------
// QUARTER-wave per edge: each lane covers uint2 (4 bf16) of the 128 B row;
// quarter q processes edges i+q. One dwordx2 gather covers 4 edges (vs the
// old 2 B/lane ushort gather = 1 edge). Softmax reduced over 16 lanes;
// output written as 10 x float4 per node (coalesced 160 B).

__global__ void k_agg2(const int2* __restrict__ rec, const int* __restrict__ rowptr,
                       const int* __restrict__ deg, const uint2* __restrict__ m2v,
                       const float* __restrict__ b2, float* __restrict__ out) {
    int node = blockIdx.x * 4 + (threadIdx.x >> 6);
    int lane = threadIdx.x & 63;
    if (node >= N_NODES) return;
    int q = lane >> 4, l16 = lane & 15;
    int start = rowptr[node], cnt = deg[node];

    float a0 = 0.f, a1 = 0.f, a2 = 0.f, a3 = 0.f;
    float c0 = 0.f, c1 = 0.f, c2 = 0.f, c3 = 0.f;

    int nmain = cnt >> 3; // 8 edges per iter (2 per quarter)
    int ebase = start + q;
    for (int k = 0; k < nmain; k++) {
        int e = ebase + (k << 3);
        int2 r0 = rec[e];
        int2 r1 = rec[e + 4];
        uint2 g0 = m2v[(long)r0.x * 16 + l16];
        uint2 g1 = m2v[(long)r1.x * 16 + l16];
        float w0 = __int_as_float(r0.y), w1 = __int_as_float(r1.y);
        a0 = fmaf(w0, bflo(g0.x), a0); a1 = fmaf(w0, bfhi(g0.x), a1);
        a2 = fmaf(w0, bflo(g0.y), a2); a3 = fmaf(w0, bfhi(g0.y), a3);
        c0 = fmaf(w1, bflo(g1.x), c0); c1 = fmaf(w1, bfhi(g1.x), c1);
        c2 = fmaf(w1, bflo(g1.y), c2); c3 = fmaf(w1, bfhi(g1.y), c3);
    }
    for (int e = start + (nmain << 3) + q; e < start + cnt; e += 4) {
        int2 r = rec[e];
        uint2 g = m2v[(long)r.x * 16 + l16];
        float w = __int_as_float(r.y);
        a0 = fmaf(w, bflo(g.x), a0); a1 = fmaf(w, bfhi(g.x), a1);
        a2 = fmaf(w, bflo(g.y), a2); a3 = fmaf(w, bfhi(g.y), a3);
    }
    a0 += c0; a1 += c1; a2 += c2; a3 += c3;
    // sum across quarters -> every lane holds full sums for features 4*l16..+3
    a0 += __shfl_xor(a0, 16); a0 += __shfl_xor(a0, 32);
    a1 += __shfl_xor(a1, 16); a1 += __shfl_xor(a1, 32);
    a2 += __shfl_xor(a2, 16); a2 += __shfl_xor(a2, 32);
    a3 += __shfl_xor(a3, 16); a3 += __shfl_xor(a3, 32);

    const float NEG = -3.4e38f;
    float v0 = NEG, v1 = NEG, v2 = NEG, v3 = NEG;
    if (l16 < 10) { // features 4*l16..+3 all < 40
        float4 bv = ((const float4*)b2)[l16];
        v0 = a0 + bv.x; v1 = a1 + bv.y; v2 = a2 + bv.z; v3 = a3 + bv.w;
    }
    float m = fmaxf(fmaxf(v0, v1), fmaxf(v2, v3));
#pragma unroll
    for (int off = 1; off < 16; off <<= 1) m = fmaxf(m, __shfl_xor(m, off));
    float s = 0.f;
    if (l16 < 10)
        s = __expf(v0 - m) + __expf(v1 - m) + __expf(v2 - m) + __expf(v3 - m);
#pragma unroll
    for (int off = 1; off < 16; off <<= 1) s += __shfl_xor(s, off);
    if (q == 0 && l16 < 10) {
        float ls = m + __logf(s);
        float4 o;
        o.x = v0 - ls; o.y = v1 - ls; o.z = v2 - ls; o.w = v3 - ls;
        ((float4*)out)[(long)node * 10 + l16] = o;
    }
}

// ---------------- launch ----------------

extern "C" void kernel_launch(void* const* d_in, const int* in_sizes, int n_in,
                              void* d_out, int out_size, void* d_ws, size_t ws_size,
                              hipStream_t stream) {
    const float* x  = (const float*)d_in[0];
    const int* ei   = (const int*)d_in[1]; // [2, E]: src then dst (int32)
    const int* src  = ei;
    const int* dst  = ei + N_EDGES;
    const float* ew = (const float*)d_in[2];
    const float* W1 = (const float*)d_in[3];
    const float* b1 = (const float*)d_in[4];
    const float* W2 = (const float*)d_in[5];
    const float* b2 = (const float*)d_in[6];
    float* out = (float*)d_out;

    char* ws = (char*)d_ws;
    size_t off = 0;
    auto alloc = [&](size_t bytes) {
        void* p = ws + off;
        off += (bytes + 255) & ~(size_t)255;
        return p;
    };
    unsigned short* m1b  = (unsigned short*)alloc((size_t)N_NODES * F_HID * 2); // 25.6 MB
    unsigned int*   h    = (unsigned int*)alloc((size_t)N_NODES * F_HID * 2);   // 25.6 MB
    unsigned short* m2b  = (unsigned short*)alloc((size_t)N_NODES * 64 * 2);    // 12.8 MB
    int2*           rec  = (int2*)alloc((size_t)N_EDGES * 8);                   // 12.8 MB
    int*          rowptr = (int*)alloc((size_t)N_NODES * 4);
    int*          deg    = (int*)alloc((size_t)N_NODES * 4);
    int*          bCnt   = (int*)alloc(512 * 4);
    int*          bBase  = (int*)alloc(512 * 4);
    int*          bCur   = (int*)alloc(512 * 4);
    short*        WT1    = (short*)alloc((size_t)F_HID * F_IN * 2);
    short*        WT2    = (short*)alloc((size_t)F_OUT_PAD * F_HID * 2);

    // tmp (bucket-major edge records) aliases m2b: both 12.8 MB; tmp is dead
    // before k_gemm2 writes m2b.
    int2* tmp = (int2*)m2b;

    hipMemsetAsync(bCnt, 0, 512 * 4, stream);

    k_bhist<<<GB + CONVB, 512, 0, stream>>>(dst, bCnt, W1, WT1, W2, WT2);
    k_bscan<<<1, 512, 0, stream>>>(bCnt, bBase, bCur);
    k_bscatter<<<GB, 512, 0, stream>>>(src, dst, ew, bCur, tmp);
    k_fine<<<NB, 256, 0, stream>>>(tmp, bBase, rec, rowptr, deg);

    k_gemm1<<<(N_NODES + 63) / 64, 256, 0, stream>>>(x, WT1, m1b);
    k_agg1<<<(N_NODES + 3) / 4, 256, 0, stream>>>(rec, rowptr, deg,
                                                  (const uint2*)m1b, b1, (uint2*)h);
    k_gemm2<<<(N_NODES + 63) / 64, 256, 0, stream>>>((const unsigned short*)h, WT2, m2b);
    k_agg2<<<(N_NODES + 3) / 4, 256, 0, stream>>>(rec, rowptr, deg,
                                                  (const uint2*)m2b, b2, out);
}